// Round 1
// baseline (245.050 us; speedup 1.0000x reference)
//
#include <hip/hip_runtime.h>

#define BB 32
#define NN 512
#define PP 128

// u[p] = sum_q relu(t[q]) * W3[q][p];  v[p] = sum_q relu(-t[q]) * W3[q][p]
__global__ void k_uv(const float* __restrict__ theta4, const float* __restrict__ W3,
                     float* __restrict__ uv) {
    int p = threadIdx.x;
    float u = 0.f, v = 0.f;
    for (int q = 0; q < PP; ++q) {
        float t = theta4[q];
        float w = W3[q * PP + p];
        u += fmaxf(t, 0.f) * w;
        v += fmaxf(-t, 0.f) * w;
    }
    uv[p] = u;
    uv[PP + p] = v;
}

// pos[b,j] = sum_i relu(weight[b,i,j]*adj[b,i,j]);  neg likewise with -w.
// Threads parallel over j -> fixed-i reads are contiguous in j (coalesced).
__global__ __launch_bounds__(256) void k_posneg(const float* __restrict__ weight,
                                                const float* __restrict__ adj,
                                                float* __restrict__ pos,
                                                float* __restrict__ neg) {
    int b = blockIdx.y;
    int j = blockIdx.x * blockDim.x + threadIdx.x;
    const float* wbase = weight + (size_t)b * NN * NN + j;
    const float* abase = adj + (size_t)b * NN * NN + j;
    float ps = 0.f, ng = 0.f;
#pragma unroll 4
    for (int i = 0; i < NN; ++i) {
        float w = wbase[(size_t)i * NN] * abase[(size_t)i * NN];
        ps += fmaxf(w, 0.f);
        ng += fmaxf(-w, 0.f);
    }
    pos[b * NN + j] = ps;
    neg[b * NN + j] = ng;
}

// One block (128 threads) per (b,j): thread p owns output element p.
// agg[b,j,p] = sum_i adj[b,j,i]*mu[b,i,p]   (adj symmetric -> row access)
// out = relu(unit1 + agg@W2 + b2 + pos*u + neg*v + b3)
__global__ __launch_bounds__(128) void k_main(
    const float* __restrict__ x, const float* __restrict__ mu,
    const float* __restrict__ adj,
    const float* __restrict__ W1, const float* __restrict__ b1,
    const float* __restrict__ W2, const float* __restrict__ b2,
    const float* __restrict__ b3,
    const float* __restrict__ uv, const float* __restrict__ pos,
    const float* __restrict__ neg, float* __restrict__ out)
{
    int j = blockIdx.x;
    int b = blockIdx.y;
    int p = threadIdx.x;

    __shared__ float adjrow[NN];
    __shared__ float aggL[PP];

    // stage adj row (512 floats) via float4: 128 threads * 16B
    const float* arow = adj + ((size_t)b * NN + j) * NN;
    ((float4*)adjrow)[p] = ((const float4*)arow)[p];
    __syncthreads();

    // sparse accumulate over neighbors (adj value is block-uniform -> uniform branch)
    float acc = 0.f;
    const float* mub = mu + (size_t)b * NN * PP;
#pragma unroll 4
    for (int i = 0; i < NN; ++i) {
        float a = adjrow[i];
        if (a != 0.f) acc += a * mub[(size_t)i * PP + p];
    }
    aggL[p] = acc;
    __syncthreads();

    // unit2 = aggL @ W2 + b2  (W2 is 64KB, L1/L2-resident; reads coalesced over p)
    float s = b2[p];
#pragma unroll 8
    for (int q = 0; q < PP; ++q) s += aggL[q] * W2[q * PP + p];

    // unit1
    s += x[b * NN + j] * W1[p] + b1[p];

    // unit3 = pos*u + neg*v + b3
    int bj = b * NN + j;
    s += pos[bj] * uv[p] + neg[bj] * uv[PP + p] + b3[p];

    out[((size_t)bj) * PP + p] = fmaxf(s, 0.f);
}

extern "C" void kernel_launch(void* const* d_in, const int* in_sizes, int n_in,
                              void* d_out, int out_size, void* d_ws, size_t ws_size,
                              hipStream_t stream) {
    const float* x      = (const float*)d_in[0];
    const float* mu     = (const float*)d_in[1];
    const float* weight = (const float*)d_in[2];
    const float* adj    = (const float*)d_in[3];
    const float* W1     = (const float*)d_in[4];
    const float* b1     = (const float*)d_in[5];
    const float* W2     = (const float*)d_in[6];
    const float* b2     = (const float*)d_in[7];
    const float* W3     = (const float*)d_in[8];
    const float* b3     = (const float*)d_in[9];
    const float* theta4 = (const float*)d_in[10];
    float* out = (float*)d_out;

    float* ws  = (float*)d_ws;
    float* uv  = ws;                  // 256 floats
    float* pos = ws + 256;            // B*N floats
    float* neg = ws + 256 + BB * NN;  // B*N floats

    k_uv<<<1, PP, 0, stream>>>(theta4, W3, uv);

    dim3 g1(NN / 256, BB);
    k_posneg<<<g1, 256, 0, stream>>>(weight, adj, pos, neg);

    dim3 g2(NN, BB);
    k_main<<<g2, PP, 0, stream>>>(x, mu, adj, W1, b1, W2, b2, b3, uv, pos, neg, out);
}

// Round 2
// 129.293 us; speedup vs baseline: 1.8953x; 1.8953x over previous
//
#include <hip/hip_runtime.h>

#define BB 32
#define NN 512
#define PP 128
#define MM (BB * NN)  // 16384 rows

typedef unsigned long long ull;

// ws layout (float offsets)
#define POSP_OFF 0            // [8][MM] f32
#define NEGP_OFF (8 * MM)     // [8][MM] f32
#define UVB_OFF (16 * MM)     // u[128], v[128], bias[128]
#define MASK_OFF_BYTES ((size_t)(16 * MM + 512) * 4)  // [8][MM] u64, 8B-aligned

// u[p] = sum_q relu(t[q])*W3[q][p]; v likewise with -t; bias = b1+b2+b3
__global__ void k_uv(const float* __restrict__ t4, const float* __restrict__ W3,
                     const float* __restrict__ b1, const float* __restrict__ b2,
                     const float* __restrict__ b3, float* __restrict__ uvb) {
    int p = threadIdx.x;
    float u = 0.f, v = 0.f;
    for (int q = 0; q < PP; ++q) {
        float t = t4[q];
        float w = W3[q * PP + p];
        u += fmaxf(t, 0.f) * w;
        v += fmaxf(-t, 0.f) * w;
    }
    uvb[p] = u;
    uvb[PP + p] = v;
    uvb[2 * PP + p] = b1[p] + b2[p] + b3[p];
}

// Per (b, i-segment, j): partial pos/neg + 64-bit neighbor mask word.
// adj symmetric: column mask over i == row mask. adj values are exactly 0/1.
__global__ __launch_bounds__(256) void k_prep(const float* __restrict__ weight,
                                              const float* __restrict__ adj,
                                              float* __restrict__ posP,
                                              float* __restrict__ negP,
                                              ull* __restrict__ maskb) {
    int b = blockIdx.z, seg = blockIdx.y;
    int j = blockIdx.x * 256 + threadIdx.x;
    size_t base = (size_t)b * NN * NN + (size_t)seg * 64 * NN + j;
    const float* wp = weight + base;
    const float* ap = adj + base;
    float ps = 0.f, ng = 0.f;
    ull m = 0;
#pragma unroll 8
    for (int k = 0; k < 64; ++k) {
        float a = ap[(size_t)k * NN];
        float w = wp[(size_t)k * NN];
        if (a != 0.f) {
            m |= (1ull << k);
            ps += fmaxf(w, 0.f);
            ng += fmaxf(-w, 0.f);
        }
    }
    int row = b * NN + j;
    posP[seg * MM + row] = ps;
    negP[seg * MM + row] = ng;
    maskb[(size_t)seg * MM + row] = m;
}

// Fused: sparse agg (mask-driven gather of mu rows) -> LDS tile -> @W2 -> epilogue.
// 512 threads = 8 waves; 32 rows (same b) per block; wave w owns rows w*4..w*4+3.
__global__ __launch_bounds__(512) void k_main(
    const float* __restrict__ x, const float* __restrict__ mu,
    const float* __restrict__ W1, const float* __restrict__ W2,
    const float* __restrict__ posP, const float* __restrict__ negP,
    const float* __restrict__ uvb, const ull* __restrict__ maskb,
    float* __restrict__ out) {
    __shared__ float aggL[32 * 130];  // pad 130: conflict-free 4-addr broadcast reads

    int bid = blockIdx.x;
    int vbid = ((bid & 7) << 6) | (bid >> 3);  // XCD swizzle: 8 chunks of 64 blocks (4 b's each)
    int row0 = vbid * 32;
    int b = row0 >> 9;
    int tx = threadIdx.x;
    int lane = tx & 63, w = tx >> 6;

    const float2* mub2 = (const float2*)(mu + (size_t)b * NN * PP);

    // ---- phase 1: agg[row][p] = sum_{i in mask} mu[b,i,p] ----
    for (int rr = 0; rr < 4; ++rr) {
        int rloc = w * 4 + rr;
        int row = row0 + rloc;
        float ax = 0.f, ay = 0.f;
#pragma unroll
        for (int r = 0; r < 8; ++r) {
            uint2 mw = ((const uint2*)maskb)[(size_t)r * MM + row];
            unsigned lo = __builtin_amdgcn_readfirstlane(mw.x);
            unsigned hi = __builtin_amdgcn_readfirstlane(mw.y);
            ull mask = ((ull)hi << 32) | lo;
            int ib = r * 64;
            while (mask) {
                int i0 = __builtin_ctzll(mask);
                mask &= mask - 1;
                float2 v0 = mub2[(size_t)((ib + i0) << 6) | lane];
                if (mask) {
                    int i1 = __builtin_ctzll(mask);
                    mask &= mask - 1;
                    float2 v1 = mub2[(size_t)((ib + i1) << 6) | lane];
                    ax += v0.x; ay += v0.y;
                    ax += v1.x; ay += v1.y;
                } else {
                    ax += v0.x; ay += v0.y;
                }
            }
        }
        *(float2*)&aggL[rloc * 130 + 2 * lane] = make_float2(ax, ay);
    }
    __syncthreads();

    // ---- phase 2: out = relu(agg@W2 + x*W1 + pos*u + neg*v + bias) ----
    int colg = tx & 15, rowg = tx >> 4;
    int p0 = colg * 8;
    float c[8] = {0.f, 0.f, 0.f, 0.f, 0.f, 0.f, 0.f, 0.f};
    const float* agr = &aggL[rowg * 130];
#pragma unroll 4
    for (int q = 0; q < PP; ++q) {
        float a = agr[q];
        const float4 w0 = *(const float4*)&W2[q * PP + p0];
        const float4 w1 = *(const float4*)&W2[q * PP + p0 + 4];
        c[0] += a * w0.x; c[1] += a * w0.y; c[2] += a * w0.z; c[3] += a * w0.w;
        c[4] += a * w1.x; c[5] += a * w1.y; c[6] += a * w1.z; c[7] += a * w1.w;
    }

    int row = row0 + rowg;
    float xs = x[row];
    float ps = 0.f, ng = 0.f;
#pragma unroll
    for (int s = 0; s < 8; ++s) {
        ps += posP[s * MM + row];
        ng += negP[s * MM + row];
    }
#pragma unroll
    for (int k = 0; k < 8; ++k) {
        int p = p0 + k;
        float o = c[k] + xs * W1[p] + ps * uvb[p] + ng * uvb[PP + p] + uvb[2 * PP + p];
        out[(size_t)row * PP + p] = fmaxf(o, 0.f);
    }
}

extern "C" void kernel_launch(void* const* d_in, const int* in_sizes, int n_in,
                              void* d_out, int out_size, void* d_ws, size_t ws_size,
                              hipStream_t stream) {
    const float* x      = (const float*)d_in[0];
    const float* mu     = (const float*)d_in[1];
    const float* weight = (const float*)d_in[2];
    const float* adj    = (const float*)d_in[3];
    const float* W1     = (const float*)d_in[4];
    const float* b1     = (const float*)d_in[5];
    const float* W2     = (const float*)d_in[6];
    const float* b2     = (const float*)d_in[7];
    const float* W3     = (const float*)d_in[8];
    const float* b3     = (const float*)d_in[9];
    const float* theta4 = (const float*)d_in[10];
    float* out = (float*)d_out;

    float* ws   = (float*)d_ws;
    float* posP = ws + POSP_OFF;
    float* negP = ws + NEGP_OFF;
    float* uvb  = ws + UVB_OFF;
    ull* maskb  = (ull*)((char*)d_ws + MASK_OFF_BYTES);

    k_uv<<<1, PP, 0, stream>>>(theta4, W3, b1, b2, b3, uvb);

    dim3 gp(NN / 256, 8, BB);
    k_prep<<<gp, 256, 0, stream>>>(weight, adj, posP, negP, maskb);

    k_main<<<MM / 32, 512, 0, stream>>>(x, mu, W1, W2, posP, negP, uvb, maskb, out);
}